// Round 11
// baseline (596.438 us; speedup 1.0000x reference)
//
#include <hip/hip_runtime.h>
#include <hip/hip_cooperative_groups.h>

namespace cg = cooperative_groups;

// ACSF G2+G4 into [N,70] f32, bin-then-gather (no f32 global atomics).
// Round-11 = round-10 resubmitted (GPU broker timeout; kernel never ran).
// Single fused cooperative kernel. Phases zero->edges->triplets->gather
// separated by grid.sync(); removes 2 memset dispatches + 4 inter-kernel
// gaps + per-node graph overhead. Internals = round-6 proven bodies
// (unsharded bins, 4 triplets/thread, int-power zeta gather).
// Coop launch failure -> round-6 separate-kernel path. ws too small ->
// direct-atomic path.
//
// ws: [trec: N*CAP_T vf2][epack: E(pad4) u32][erec: N*CAP_E u32]
//     [tcount: N int][ecount: N int]

#define CAP_T 96
#define CAP_E 64

typedef int      vi2 __attribute__((ext_vector_type(2)));
typedef int      vi4 __attribute__((ext_vector_type(4)));
typedef float    vf2 __attribute__((ext_vector_type(2)));
typedef float    vf4 __attribute__((ext_vector_type(4)));
typedef unsigned vu2 __attribute__((ext_vector_type(2)));

struct Params {
    const int*   an;
    const int*   ei;
    const float* D;
    const int*   id3_ba;
    const int*   id3_ca;
    const float* cosphi;
    const float* g2_etas;
    const float* g4_etas;
    const float* g4_zetas;
    const float* g4_lmdas;
    unsigned*    epack;
    unsigned*    erec;
    vf2*         trec;
    int*         tcount;   // [N], ecount follows at +N
    int*         ecount;
    float*       out;
    int N, E, T;
};

static __device__ __forceinline__ float fc_dev(float R) {
    const float PI_OVER_CUT = 0.52359877559829887308f;  // pi/6
    return fmaf(0.5f, __cosf(PI_OVER_CUT * R), 0.5f);
}
static __device__ __forceinline__ unsigned enc_R(float d) {
    float u = rintf(d * (65535.0f / 8.0f));
    u = fminf(fmaxf(u, 0.0f), 65535.0f);
    return (unsigned)u;
}
static __device__ __forceinline__ float dec_R(unsigned pk) {
    return (float)(pk >> 16) * (8.0f / 65535.0f);
}

// ---- phase bodies (shared by fused + separate paths) ----

static __device__ __forceinline__ void edges_item(const Params& p, int i) {
    int e0 = i * 2;
    int   srcs[2], tgts[2];
    float ds[2];
    int   nk;
    if (e0 + 1 < p.E) {
        vi2 sp = __builtin_nontemporal_load((const vi2*)p.ei + i);
        vi2 tp = __builtin_nontemporal_load((const vi2*)(p.ei + p.E) + i);
        vf2 dp = __builtin_nontemporal_load((const vf2*)p.D + i);
        srcs[0] = sp.x; srcs[1] = sp.y;
        tgts[0] = tp.x; tgts[1] = tp.y;
        ds[0] = dp.x;   ds[1] = dp.y;
        nk = 2;
    } else {
        srcs[0] = p.ei[e0]; tgts[0] = p.ei[p.E + e0]; ds[0] = p.D[e0];
        srcs[1] = 0;        tgts[1] = 0;              ds[1] = 0.0f;
        nk = 1;
    }
    int as[2];
#pragma unroll
    for (int k = 0; k < 2; ++k) as[k] = (k < nk) ? p.an[srcs[k]] : 0;
    unsigned pk[2];
#pragma unroll
    for (int k = 0; k < 2; ++k)
        pk[k] = (enc_R(ds[k]) << 16) | ((unsigned)tgts[k] << 1) | (unsigned)as[k];
    if (nk == 2) {
        vu2 pv; pv.x = pk[0]; pv.y = pk[1];
        *((vu2*)p.epack + i) = pv;
    } else {
        p.epack[e0] = pk[0];
    }
    float fcv[2];
#pragma unroll
    for (int k = 0; k < 2; ++k) fcv[k] = fc_dev(ds[k]);
    int slot[2];
#pragma unroll
    for (int k = 0; k < 2; ++k)
        slot[k] = (k < nk) ? atomicAdd(&p.ecount[tgts[k]], 1) : CAP_E;
#pragma unroll
    for (int k = 0; k < 2; ++k) {
        if (k >= nk) continue;
        if (slot[k] < CAP_E) {
            unsigned fq = (unsigned)rintf(fminf(fmaxf(fcv[k], 0.0f), 1.0f) * 32767.0f);
            p.erec[(size_t)tgts[k] * CAP_E + slot[k]] =
                (pk[k] & 0xFFFF0000u) | (fq << 1) | (pk[k] & 1u);
        } else {  // overflow fallback (rare, exact)
            float d2 = ds[k] * ds[k];
            int at = p.an[tgts[k]];
            const float* eta = p.g2_etas + (as[k] * 2 + at) * 8;
            float* row = p.out + (size_t)tgts[k] * 70 + as[k];
#pragma unroll
            for (int q = 0; q < 8; ++q)
                atomicAdd(row + 2 * q, fcv[k] * __expf(-eta[q] * d2));
        }
    }
}

static __device__ __forceinline__ void trip_item(const Params& p, int i) {
    int t0 = i * 4;
    int ba[4], ca[4];
    float cp[4];
    if (t0 + 3 < p.T) {
        vi4 b4 = __builtin_nontemporal_load((const vi4*)p.id3_ba + i);
        vi4 c4 = __builtin_nontemporal_load((const vi4*)p.id3_ca + i);
        vf4 p4 = __builtin_nontemporal_load((const vf4*)p.cosphi + i);
        ba[0] = b4.x; ba[1] = b4.y; ba[2] = b4.z; ba[3] = b4.w;
        ca[0] = c4.x; ca[1] = c4.y; ca[2] = c4.z; ca[3] = c4.w;
        cp[0] = p4.x; cp[1] = p4.y; cp[2] = p4.z; cp[3] = p4.w;
    } else {
#pragma unroll
        for (int k = 0; k < 4; ++k) {
            int t = t0 + k;
            ba[k] = (t < p.T) ? p.id3_ba[t] : 0;
            ca[k] = (t < p.T) ? p.id3_ca[t] : 1;   // ba<=ca -> masked out
            cp[k] = (t < p.T) ? p.cosphi[t] : 0.0f;
        }
    }
    unsigned pb[4], pc[4];
    bool m[4];
#pragma unroll
    for (int k = 0; k < 4; ++k) {
        m[k] = ba[k] > ca[k];                      // m3 dedup
        pb[k] = 0u; pc[k] = 0u;
        if (m[k]) {
            pb[k] = p.epack[ba[k]];
            pc[k] = p.epack[ca[k]];
        }
    }
    float Rba[4], Rca[4], Rm2[4];
    int seg[4];
    bool valid[4];
#pragma unroll
    for (int k = 0; k < 4; ++k) {
        Rba[k] = dec_R(pb[k]);
        Rca[k] = dec_R(pc[k]);
        float Rbc2 = Rba[k] * Rba[k] + Rca[k] * Rca[k]
                     - 2.0f * Rba[k] * Rca[k] * cp[k];
        Rm2[k] = fmaxf(Rbc2, 1e-12f);
        float Rbc = sqrtf(Rm2[k]);
        valid[k] = m[k] && (Rba[k] < 6.0f) && (Rca[k] < 6.0f) && (Rbc < 6.0f);
        seg[k] = (int)((pb[k] >> 1) & 0x7FFFu);
    }
    int slot[4];
#pragma unroll
    for (int k = 0; k < 4; ++k)
        slot[k] = valid[k] ? atomicAdd(&p.tcount[seg[k]], 1) : CAP_T;
#pragma unroll
    for (int k = 0; k < 4; ++k) {
        if (!valid[k]) continue;
        float r2sum = Rm2[k] + Rba[k] * Rba[k] + Rca[k] * Rca[k];
        float cut3 = fc_dev(Rba[k]) * fc_dev(Rca[k]) * fc_dev(sqrtf(Rm2[k]));
        int trip = (int)(pb[k] & 1u) + (int)(pc[k] & 1u);
        if (slot[k] < CAP_T) {
            float cqf = fminf(fmaxf(fmaf(cp[k], 32767.5f, 32767.5f), 0.0f), 65535.0f);
            unsigned cq = (unsigned)rintf(cqf);
            unsigned c3q = (unsigned)rintf(cut3 * 16383.0f);
            unsigned w0 = (cq << 16) | (c3q << 2) | (unsigned)trip;
            vf2 r; r.x = __uint_as_float(w0); r.y = r2sum;
            p.trec[(size_t)seg[k] * CAP_T + slot[k]] = r;
        } else {  // overflow fallback: 18 direct atomics (rare, exact)
            int A = p.an[seg[k]];
            int k4 = A * 3 + trip;
            const float* eta = p.g4_etas + k4 * 3;
            const float* zet = p.g4_zetas + k4 * 3;
            const float* lmd = p.g4_lmdas + k4 * 2;
            float rad[3];
#pragma unroll
            for (int e2 = 0; e2 < 3; ++e2)
                rad[e2] = __expf(-eta[e2] * r2sum) * cut3;
            float lg0 = __log2f(fabsf(fmaf(lmd[0], cp[k], 1.0f)));
            float lg1 = __log2f(fabsf(fmaf(lmd[1], cp[k], 1.0f)));
            float* row = p.out + (size_t)seg[k] * 70 + 16 + trip;
#pragma unroll
            for (int z = 0; z < 3; ++z) {
                float zv = zet[z], base = 1.0f - zv;
                float c0 = exp2f(fmaf(zv, lg0, base));
                float c1 = exp2f(fmaf(zv, lg1, base));
#pragma unroll
                for (int e2 = 0; e2 < 3; ++e2) {
                    atomicAdd(row + ((e2 * 2 + 0) * 3 + z) * 3, c0 * rad[e2]);
                    atomicAdd(row + ((e2 * 2 + 1) * 3 + z) * 3, c1 * rad[e2]);
                }
            }
        }
    }
}

// One wave handles one atom. s4: 66 vf2 slots; s2: 64 u32 slots (per wave).
static __device__ __forceinline__ void gather_atom(const Params& p, int a,
                                                   int lane, vf2* s4,
                                                   unsigned* s2) {
    int A = p.an[a];

    // ---- G4: lane = g*18 + combo; per-trip partials; 9-shuffle reduce ----
    int c18 = lane % 18;
    int g3  = lane / 18;
    int g3r = (g3 > 2) ? 0 : g3;
    int z_c = c18 % 3;
    int l_c = (c18 / 3) % 2;
    int e_c = c18 / 6;
    float eta0, eta1, eta2w, zv0, zv1, zv2, lm0, lm1, lm2;
    {
        int k0 = A * 3 + 0, k1 = A * 3 + 1, k2 = A * 3 + 2;
        eta0 = p.g4_etas[k0 * 3 + e_c]; eta1 = p.g4_etas[k1 * 3 + e_c]; eta2w = p.g4_etas[k2 * 3 + e_c];
        zv0  = p.g4_zetas[k0 * 3 + z_c]; zv1 = p.g4_zetas[k1 * 3 + z_c]; zv2 = p.g4_zetas[k2 * 3 + z_c];
        lm0  = p.g4_lmdas[k0 * 2 + l_c]; lm1 = p.g4_lmdas[k1 * 2 + l_c]; lm2 = p.g4_lmdas[k2 * 2 + l_c];
    }
    auto zsel = [](float z) -> int {
        return (z == 1.0f) ? 0 : (z == 2.0f) ? 1 : (z == 4.0f) ? 2 : 3;
    };
    int zs0 = zsel(zv0), zs1 = zsel(zv1), zs2 = zsel(zv2);
    bool fastz = __all(zs0 < 3 && zs1 < 3 && zs2 < 3);

    int n_t = min(p.tcount[a], CAP_T);
    const vf2* rec = p.trec + (size_t)a * CAP_T;
    float acc0 = 0.0f, acc1 = 0.0f, acc2 = 0.0f;
    vf2 zr; zr.x = 0.0f; zr.y = 0.0f;
    for (int b0 = 0; b0 < n_t; b0 += 64) {
        int nch = min(64, n_t - b0);
        vf2 rv = zr;
        if (lane < nch) rv = __builtin_nontemporal_load(rec + b0 + lane);
        s4[lane] = rv;
        if (lane < 2) s4[64 + lane] = zr;
        asm volatile("s_waitcnt lgkmcnt(0)" ::: "memory");
        int niter = (nch + 2) / 3;
        if (fastz) {
            for (int i = 0; i < niter; ++i) {
                vf2 b = s4[i * 3 + g3r];
                unsigned w0 = __float_as_uint(b.x);
                int btr = (int)(w0 & 3u);
                float cut3 = (float)((w0 >> 2) & 0x3FFFu) * (1.0f / 16383.0f);
                float c = fmaf((float)(w0 >> 16), 2.0f / 65535.0f, -1.0f);
                float eta_r = (btr == 0) ? eta0 : (btr == 1) ? eta1 : eta2w;
                float lm_r  = (btr == 0) ? lm0  : (btr == 1) ? lm1  : lm2;
                int   zs_r  = (btr == 0) ? zs0  : (btr == 1) ? zs1  : zs2;
                float p1 = fabsf(fmaf(lm_r, c, 1.0f));
                float p2 = p1 * p1;
                float p4 = p2 * p2;
                float cl = (zs_r == 0) ? p1 : (zs_r == 1) ? p2 * 0.5f : p4 * 0.125f;
                float v = cl * __expf(-eta_r * b.y) * cut3;
                acc0 += (btr == 0) ? v : 0.0f;
                acc1 += (btr == 1) ? v : 0.0f;
                acc2 += (btr == 2) ? v : 0.0f;
            }
        } else {
            for (int i = 0; i < niter; ++i) {
                vf2 b = s4[i * 3 + g3r];
                unsigned w0 = __float_as_uint(b.x);
                int btr = (int)(w0 & 3u);
                float cut3 = (float)((w0 >> 2) & 0x3FFFu) * (1.0f / 16383.0f);
                float c = fmaf((float)(w0 >> 16), 2.0f / 65535.0f, -1.0f);
                float eta_r = (btr == 0) ? eta0 : (btr == 1) ? eta1 : eta2w;
                float lm_r  = (btr == 0) ? lm0  : (btr == 1) ? lm1  : lm2;
                float zv_r  = (btr == 0) ? zv0  : (btr == 1) ? zv1  : zv2;
                float p1 = fabsf(fmaf(lm_r, c, 1.0f));
                float cl = exp2f(fmaf(zv_r, __log2f(p1), 1.0f - zv_r));
                float v = cl * __expf(-eta_r * b.y) * cut3;
                acc0 += (btr == 0) ? v : 0.0f;
                acc1 += (btr == 1) ? v : 0.0f;
                acc2 += (btr == 2) ? v : 0.0f;
            }
        }
    }
    {
        int cc = lane / 3;
        int tt = lane - cc * 3;
        float s0a = __shfl(acc0, cc),      s1a = __shfl(acc1, cc),      s2a = __shfl(acc2, cc);
        float s0b = __shfl(acc0, cc + 18), s1b = __shfl(acc1, cc + 18), s2b = __shfl(acc2, cc + 18);
        float s0c = __shfl(acc0, cc + 36), s1c = __shfl(acc1, cc + 36), s2c = __shfl(acc2, cc + 36);
        float va = (tt == 0) ? s0a : (tt == 1) ? s1a : s2a;
        float vb = (tt == 0) ? s0b : (tt == 1) ? s1b : s2b;
        float vc = (tt == 0) ? s0c : (tt == 1) ? s1c : s2c;
        if (lane < 54) p.out[(size_t)a * 70 + 16 + lane] += va + vb + vc;
    }

    // ---- G2: lane = g*16 + col; 4-shuffle reduce ----
    int c16 = lane & 15;
    int g4g = lane >> 4;
    int s_c = c16 & 1;
    int i_c = c16 >> 1;
    float eta2 = p.g2_etas[(s_c * 2 + A) * 8 + i_c];
    int n_e = min(p.ecount[a], CAP_E);
    const unsigned* erc = p.erec + (size_t)a * CAP_E;
    float accg = 0.0f;
    for (int b0 = 0; b0 < n_e; b0 += 64) {
        int nch = min(64, n_e - b0);
        unsigned rv = 0u;
        if (lane < nch) rv = __builtin_nontemporal_load(erc + b0 + lane);
        s2[lane] = rv;
        asm volatile("s_waitcnt lgkmcnt(0)" ::: "memory");
        int niter = (nch + 3) / 4;
        for (int i = 0; i < niter; ++i) {
            unsigned pk = s2[i * 4 + g4g];
            int sp = (int)(pk & 1u);
            float d = dec_R(pk);
            float fcv = (float)((pk >> 1) & 0x7FFFu) * (1.0f / 32767.0f);
            float v = fcv * __expf(-eta2 * d * d);
            accg += (sp == s_c) ? v : 0.0f;
        }
    }
    {
        float r0 = __shfl(accg, lane);
        float r1 = __shfl(accg, lane + 16);
        float r2 = __shfl(accg, lane + 32);
        float r3 = __shfl(accg, lane + 48);
        if (lane < 16) p.out[(size_t)a * 70 + lane] += r0 + r1 + r2 + r3;
    }
}

// ---- fused cooperative kernel ----
__global__ __launch_bounds__(256, 4) void fused_kernel(Params p) {
    cg::grid_group grid = cg::this_grid();
    int tid  = blockIdx.x * blockDim.x + threadIdx.x;
    int nthr = gridDim.x * blockDim.x;

    // phase 0: zero out + counters (tcount/ecount contiguous)
    int nz = p.N * 70;
    for (int i = tid; i < nz; i += nthr) p.out[i] = 0.0f;
    for (int i = tid; i < 2 * p.N; i += nthr) p.tcount[i] = 0;
    grid.sync();

    // phase 1: edges
    int eitems = (p.E + 1) / 2;
    for (int i = tid; i < eitems; i += nthr) edges_item(p, i);
    grid.sync();

    // phase 2: triplets
    int titems = (p.T + 3) / 4;
    for (int i = tid; i < titems; i += nthr) trip_item(p, i);
    grid.sync();

    // phase 3: gather (one wave per atom)
    __shared__ vf2      sg4[4][66];
    __shared__ unsigned sg2[4][64];
    int w = threadIdx.x >> 6;
    int lane = threadIdx.x & 63;
    for (int a = blockIdx.x * 4 + w; a < p.N; a += gridDim.x * 4)
        gather_atom(p, a, lane, sg4[w], sg2[w]);
}

// ---- separate-kernel path (coop-launch failure fallback) ----
__global__ __launch_bounds__(256) void edges_k(Params p) {
    int tid = blockIdx.x * blockDim.x + threadIdx.x;
    int stride = gridDim.x * blockDim.x;
    int items = (p.E + 1) / 2;
    for (int i = tid; i < items; i += stride) edges_item(p, i);
}
__global__ __launch_bounds__(256) void trip_k(Params p) {
    int tid = blockIdx.x * blockDim.x + threadIdx.x;
    int stride = gridDim.x * blockDim.x;
    int items = (p.T + 3) / 4;
    for (int i = tid; i < items; i += stride) trip_item(p, i);
}
__global__ __launch_bounds__(256) void gather_k(Params p) {
    __shared__ vf2      sg4[4][66];
    __shared__ unsigned sg2[4][64];
    int w = threadIdx.x >> 6;
    int lane = threadIdx.x & 63;
    for (int a = blockIdx.x * 4 + w; a < p.N; a += gridDim.x * 4)
        gather_atom(p, a, lane, sg4[w], sg2[w]);
}

// ---- direct-atomic path (ws too small) ----
__global__ void acsf_edges_kernel(const int* __restrict__ an,
                                  const int* __restrict__ ei,
                                  const float* __restrict__ D,
                                  const float* __restrict__ g2_etas,
                                  float2* __restrict__ edata,
                                  float* __restrict__ out,
                                  int E, int use_ws) {
    int e = blockIdx.x * blockDim.x + threadIdx.x;
    if (e >= E) return;
    float d = D[e];
    float cut2 = fc_dev(d);
    if (use_ws) edata[e] = make_float2(d, cut2);
    int src = ei[e];
    int tgt = ei[E + e];
    int as = an[src];
    int at = an[tgt];
    float d2 = d * d;
    const float* eta = g2_etas + (as * 2 + at) * 8;
    float* row = out + (size_t)tgt * 70 + as;
#pragma unroll
    for (int i = 0; i < 8; ++i)
        atomicAdd(row + 2 * i, cut2 * __expf(-eta[i] * d2));
}

__global__ void acsf_triplets_kernel(const int* __restrict__ an,
                                     const int* __restrict__ ei,
                                     const float* __restrict__ D,
                                     const float2* __restrict__ edata,
                                     const int* __restrict__ id3_ba,
                                     const int* __restrict__ id3_ca,
                                     const float* __restrict__ cosphi,
                                     const float* __restrict__ g4_etas,
                                     const float* __restrict__ g4_zetas,
                                     const float* __restrict__ g4_lmdas,
                                     float* __restrict__ out,
                                     int T, int E, int use_ws) {
    int t = blockIdx.x * blockDim.x + threadIdx.x;
    if (t >= T) return;
    int eba = id3_ba[t];
    int eca = id3_ca[t];
    if (eba <= eca) return;
    float R_ba, R_ca, fba, fca;
    if (use_ws) {
        float2 va = edata[eba];
        float2 vb = edata[eca];
        R_ba = va.x; fba = va.y;
        R_ca = vb.x; fca = vb.y;
    } else {
        R_ba = D[eba]; R_ca = D[eca];
        fba = fc_dev(R_ba); fca = fc_dev(R_ca);
    }
    if (R_ba >= 6.0f || R_ca >= 6.0f) return;
    float cph = cosphi[t];
    float Rbc2 = R_ba * R_ba + R_ca * R_ca - 2.0f * R_ba * R_ca * cph;
    float Rm2 = fmaxf(Rbc2, 1e-12f);
    float R_bc = sqrtf(Rm2);
    if (R_bc >= 6.0f) return;
    int seg = ei[E + eba];
    int A = an[seg];
    int sb = an[ei[eba]];
    int sc = an[ei[eca]];
    int trip = sb + sc;
    int k4 = A * 3 + trip;
    float cut3 = fba * fca * fc_dev(R_bc);
    float r2sum = Rm2 + R_ba * R_ba + R_ca * R_ca;
    const float* eta = g4_etas + k4 * 3;
    const float* zet = g4_zetas + k4 * 3;
    const float* lmd = g4_lmdas + k4 * 2;
    float rad[3];
#pragma unroll
    for (int e2 = 0; e2 < 3; ++e2)
        rad[e2] = __expf(-eta[e2] * r2sum) * cut3;
    float lg0 = __log2f(fabsf(fmaf(lmd[0], cph, 1.0f)));
    float lg1 = __log2f(fabsf(fmaf(lmd[1], cph, 1.0f)));
    float* row = out + (size_t)seg * 70 + 16 + trip;
#pragma unroll
    for (int z = 0; z < 3; ++z) {
        float zv = zet[z], bse = 1.0f - zv;
        float c0 = exp2f(fmaf(zv, lg0, bse));
        float c1 = exp2f(fmaf(zv, lg1, bse));
#pragma unroll
        for (int e2 = 0; e2 < 3; ++e2) {
            atomicAdd(row + ((e2 * 2 + 0) * 3 + z) * 3, c0 * rad[e2]);
            atomicAdd(row + ((e2 * 2 + 1) * 3 + z) * 3, c1 * rad[e2]);
        }
    }
}

// ---------------- host ----------------

extern "C" void kernel_launch(void* const* d_in, const int* in_sizes, int n_in,
                              void* d_out, int out_size, void* d_ws, size_t ws_size,
                              hipStream_t stream) {
    const int*   an       = (const int*)d_in[0];
    const int*   ei       = (const int*)d_in[1];
    const float* D        = (const float*)d_in[2];
    const int*   id3_ba   = (const int*)d_in[3];
    const int*   id3_ca   = (const int*)d_in[4];
    const float* cosphi   = (const float*)d_in[5];
    const float* g2_etas  = (const float*)d_in[6];
    const float* g4_etas  = (const float*)d_in[7];
    const float* g4_zetas = (const float*)d_in[8];
    const float* g4_lmdas = (const float*)d_in[9];
    (void)n_in;

    int N = in_sizes[0];
    int E = in_sizes[2];
    int T = in_sizes[3];
    float* out = (float*)d_out;

    size_t trec_b  = (size_t)N * CAP_T * sizeof(vf2);
    size_t epack_b = (size_t)((E + 3) & ~3) * sizeof(unsigned);
    size_t erec_b  = (size_t)N * CAP_E * sizeof(unsigned);
    size_t cnt_b   = (size_t)2 * N * sizeof(int);
    size_t need = trec_b + epack_b + erec_b + cnt_b;

    const int blk = 256;

    if (ws_size >= need && N <= 32767) {
        char* pws = (char*)d_ws;
        vf2*      trec  = (vf2*)pws;           pws += trec_b;
        unsigned* epack = (unsigned*)pws;      pws += epack_b;
        unsigned* erec  = (unsigned*)pws;      pws += erec_b;
        int*      tcount = (int*)pws;
        int*      ecount = tcount + N;

        Params prm;
        prm.an = an; prm.ei = ei; prm.D = D;
        prm.id3_ba = id3_ba; prm.id3_ca = id3_ca; prm.cosphi = cosphi;
        prm.g2_etas = g2_etas; prm.g4_etas = g4_etas;
        prm.g4_zetas = g4_zetas; prm.g4_lmdas = g4_lmdas;
        prm.epack = epack; prm.erec = erec; prm.trec = trec;
        prm.tcount = tcount; prm.ecount = ecount;
        prm.out = out; prm.N = N; prm.E = E; prm.T = T;

        void* args[] = { (void*)&prm };
        hipError_t rc = hipLaunchCooperativeKernel(
            (const void*)fused_kernel, dim3(1024), dim3(blk), args, 0, stream);
        if (rc != hipSuccess) {
            // separate-kernel fallback (round-6 style)
            (void)hipMemsetAsync(d_out, 0, (size_t)out_size * sizeof(float), stream);
            (void)hipMemsetAsync(tcount, 0, cnt_b, stream);
            int egrid = ((E + 1) / 2 + blk - 1) / blk;
            int tgrid = ((T + 3) / 4 + blk - 1) / blk;
            int ggrid = (N + 3) / 4;
            edges_k<<<egrid, blk, 0, stream>>>(prm);
            trip_k<<<tgrid, blk, 0, stream>>>(prm);
            gather_k<<<ggrid, blk, 0, stream>>>(prm);
        }
    } else {
        (void)hipMemsetAsync(d_out, 0, (size_t)out_size * sizeof(float), stream);
        int use_ws = (ws_size >= (size_t)E * sizeof(float2)) ? 1 : 0;
        float2* edata = (float2*)d_ws;
        acsf_edges_kernel<<<(E + blk - 1) / blk, blk, 0, stream>>>(
            an, ei, D, g2_etas, edata, out, E, use_ws);
        acsf_triplets_kernel<<<(T + blk - 1) / blk, blk, 0, stream>>>(
            an, ei, D, edata, id3_ba, id3_ca, cosphi,
            g4_etas, g4_zetas, g4_lmdas, out, T, E, use_ws);
    }
}

// Round 12
// 184.872 us; speedup vs baseline: 3.2262x; 3.2262x over previous
//
#include <hip/hip_runtime.h>

// ACSF G2+G4 into [N,70] f32, bin-then-gather (no f32 global atomics).
// Round-12: REVERT to round-6 architecture (best proven 186.6us).
// Round-11's fused cooperative kernel was 3x slower (500us) at identical
// traffic -> coop launch forces cross-XCD-coherent memory semantics on
// MI355X; grid.sync is off the table. The 3-kernel + 2-memset pipeline is
// the structural floor (each phase consumes the previous phase's complete
// output at arbitrary indices).
// Tweaks vs round-6: CAP_T 96->64, CAP_E 64->56 (observed maxima ~57/~48,
// 5.5-sigma margin, exact overflow fallback kept) -> denser trec (512B/atom,
// fewer gather lines) and 17MB ws (less re-poison).
//
// ws: [trec: N*CAP_T vf2][epack: E(pad2) u32][erec: N*CAP_E u32]
//     [tcount: N int][ecount: N int]

#define CAP_T 64
#define CAP_E 56

typedef int      vi2 __attribute__((ext_vector_type(2)));
typedef int      vi4 __attribute__((ext_vector_type(4)));
typedef float    vf2 __attribute__((ext_vector_type(2)));
typedef float    vf4 __attribute__((ext_vector_type(4)));
typedef unsigned vu2 __attribute__((ext_vector_type(2)));

static __device__ __forceinline__ float fc_dev(float R) {
    const float PI_OVER_CUT = 0.52359877559829887308f;  // pi/6
    return fmaf(0.5f, __cosf(PI_OVER_CUT * R), 0.5f);
}

// R packed as u16 over [0,8): err <= 6.1e-5
static __device__ __forceinline__ unsigned enc_R(float d) {
    float u = rintf(d * (65535.0f / 8.0f));
    u = fminf(fmaxf(u, 0.0f), 65535.0f);
    return (unsigned)u;
}
static __device__ __forceinline__ float dec_R(unsigned pk) {
    return (float)(pk >> 16) * (8.0f / 65535.0f);
}

// ---------------- binned path ----------------

static __device__ __forceinline__ void process_edge(
        int e, float d, int src, int tgt,
        const int* __restrict__ an, const float* __restrict__ g2_etas,
        unsigned* __restrict__ epack, int* __restrict__ ecount,
        unsigned* __restrict__ erec, float* __restrict__ out) {
    int as = an[src];
    unsigned dq = enc_R(d);
    epack[e] = (dq << 16) | ((unsigned)tgt << 1) | (unsigned)as;
    float fcv = fc_dev(d);
    int slot = atomicAdd(&ecount[tgt], 1);
    if (slot < CAP_E) {
        // erec: [31:16]=d_q u16, [15:1]=fc_q u15, [0]=species
        unsigned fq = (unsigned)rintf(fminf(fmaxf(fcv, 0.0f), 1.0f) * 32767.0f);
        erec[(size_t)tgt * CAP_E + slot] = (dq << 16) | (fq << 1) | (unsigned)as;
    } else {  // overflow fallback (exact; ~never at CAP_E=56 vs max ~48)
        float d2 = d * d;
        int at = an[tgt];
        const float* eta = g2_etas + (as * 2 + at) * 8;
        float* row = out + (size_t)tgt * 70 + as;
#pragma unroll
        for (int i = 0; i < 8; ++i)
            atomicAdd(row + 2 * i, fcv * __expf(-eta[i] * d2));
    }
}

// Two edges per thread; NT stream loads.
__global__ void edges_bin_kernel(const int* __restrict__ an,
                                 const int* __restrict__ ei,
                                 const float* __restrict__ D,
                                 const float* __restrict__ g2_etas,
                                 unsigned* __restrict__ epack,
                                 int* __restrict__ ecount,
                                 unsigned* __restrict__ erec,
                                 float* __restrict__ out, int E) {
    int i = blockIdx.x * blockDim.x + threadIdx.x;
    int e0 = i * 2;
    if (e0 >= E) return;
    if (e0 + 1 < E) {
        vi2 sp = __builtin_nontemporal_load((const vi2*)ei + i);
        vi2 tp = __builtin_nontemporal_load((const vi2*)(ei + E) + i);
        vf2 dp = __builtin_nontemporal_load((const vf2*)D + i);
        process_edge(e0,     dp.x, sp.x, tp.x, an, g2_etas, epack, ecount, erec, out);
        process_edge(e0 + 1, dp.y, sp.y, tp.y, an, g2_etas, epack, ecount, erec, out);
    } else {
        process_edge(e0, D[e0], ei[e0], ei[E + e0], an, g2_etas, epack, ecount,
                     erec, out);
    }
}

static __device__ __forceinline__ void process_triplet(
        unsigned pb, unsigned pc, float cph,
        const int* __restrict__ an,
        const float* __restrict__ g4_etas,
        const float* __restrict__ g4_zetas,
        const float* __restrict__ g4_lmdas,
        int* __restrict__ tcount, vf2* __restrict__ trec,
        float* __restrict__ out) {
    float R_ba = dec_R(pb);
    float R_ca = dec_R(pc);
    if (R_ba >= 6.0f || R_ca >= 6.0f) return;     // in_range (fc->0 at 6)
    float Rbc2 = R_ba * R_ba + R_ca * R_ca - 2.0f * R_ba * R_ca * cph;
    float Rm2 = fmaxf(Rbc2, 1e-12f);
    float R_bc = sqrtf(Rm2);
    if (R_bc >= 6.0f) return;
    int seg = (int)((pb >> 1) & 0x7FFFu);
    int trip = (int)(pb & 1u) + (int)(pc & 1u);
    float cut3 = fc_dev(R_ba) * fc_dev(R_ca) * fc_dev(R_bc);
    float r2sum = Rm2 + R_ba * R_ba + R_ca * R_ca;
    int slot = atomicAdd(&tcount[seg], 1);
    if (slot < CAP_T) {
        float cqf = fminf(fmaxf(fmaf(cph, 32767.5f, 32767.5f), 0.0f), 65535.0f);
        unsigned cq = (unsigned)rintf(cqf);
        unsigned c3q = (unsigned)rintf(cut3 * 16383.0f);
        unsigned w0 = (cq << 16) | (c3q << 2) | (unsigned)trip;
        vf2 r; r.x = __uint_as_float(w0); r.y = r2sum;
        trec[(size_t)seg * CAP_T + slot] = r;
    } else {  // overflow fallback: 18 direct atomics (exact; ~never at CAP_T=64)
        int A = an[seg];
        int k4 = A * 3 + trip;
        const float* eta = g4_etas + k4 * 3;
        const float* zet = g4_zetas + k4 * 3;
        const float* lmd = g4_lmdas + k4 * 2;
        float rad[3];
#pragma unroll
        for (int e2 = 0; e2 < 3; ++e2)
            rad[e2] = __expf(-eta[e2] * r2sum) * cut3;
        float lg0 = __log2f(fabsf(fmaf(lmd[0], cph, 1.0f)));
        float lg1 = __log2f(fabsf(fmaf(lmd[1], cph, 1.0f)));
        float* row = out + (size_t)seg * 70 + 16 + trip;
#pragma unroll
        for (int z = 0; z < 3; ++z) {
            float zv = zet[z], base = 1.0f - zv;
            float c0 = exp2f(fmaf(zv, lg0, base));
            float c1 = exp2f(fmaf(zv, lg1, base));
#pragma unroll
            for (int e2 = 0; e2 < 3; ++e2) {
                atomicAdd(row + ((e2 * 2 + 0) * 3 + z) * 3, c0 * rad[e2]);
                atomicAdd(row + ((e2 * 2 + 1) * 3 + z) * 3, c1 * rad[e2]);
            }
        }
    }
}

// Four triplets per thread: NT vector stream loads, batched predicated
// gathers into the 2MB epack table, then 4 independent process chains.
__global__ void trip_bin_kernel(const unsigned* __restrict__ epack,
                                const int* __restrict__ id3_ba,
                                const int* __restrict__ id3_ca,
                                const float* __restrict__ cosphi,
                                const int* __restrict__ an,
                                const float* __restrict__ g4_etas,
                                const float* __restrict__ g4_zetas,
                                const float* __restrict__ g4_lmdas,
                                int* __restrict__ tcount,
                                vf2* __restrict__ trec,
                                float* __restrict__ out, int T) {
    int i = blockIdx.x * blockDim.x + threadIdx.x;
    int t0 = i * 4;
    if (t0 >= T) return;
    int ba[4], ca[4];
    float cp[4];
    if (t0 + 3 < T) {
        vi4 b4 = __builtin_nontemporal_load((const vi4*)id3_ba + i);
        vi4 c4 = __builtin_nontemporal_load((const vi4*)id3_ca + i);
        vf4 p4 = __builtin_nontemporal_load((const vf4*)cosphi + i);
        ba[0] = b4.x; ba[1] = b4.y; ba[2] = b4.z; ba[3] = b4.w;
        ca[0] = c4.x; ca[1] = c4.y; ca[2] = c4.z; ca[3] = c4.w;
        cp[0] = p4.x; cp[1] = p4.y; cp[2] = p4.z; cp[3] = p4.w;
    } else {
#pragma unroll
        for (int k = 0; k < 4; ++k) {
            int t = t0 + k;
            ba[k] = (t < T) ? id3_ba[t] : 0;
            ca[k] = (t < T) ? id3_ca[t] : 1;   // ba<=ca -> masked out
            cp[k] = (t < T) ? cosphi[t] : 0.0f;
        }
    }
    unsigned pb[4], pc[4];
    bool m[4];
#pragma unroll
    for (int k = 0; k < 4; ++k) {
        m[k] = ba[k] > ca[k];                      // m3 dedup
        pb[k] = 0u; pc[k] = 0u;
        if (m[k]) {
            pb[k] = epack[ba[k]];
            pc[k] = epack[ca[k]];
        }
    }
#pragma unroll
    for (int k = 0; k < 4; ++k) {
        if (m[k])
            process_triplet(pb[k], pc[k], cp[k], an, g4_etas, g4_zetas,
                            g4_lmdas, tcount, trec, out);
    }
}

// One wave per atom. G4: lane = g*18 + combo processes record 3*i+g each
// iteration, per-trip partials acc0/1/2, 9-shuffle reduce to columns.
// G2: lane = g*16 + col, record 4*i+g, 4-shuffle reduce.
__global__ __launch_bounds__(256) void gather_kernel(
        const int* __restrict__ an,
        const float* __restrict__ g2_etas,
        const float* __restrict__ g4_etas,
        const float* __restrict__ g4_zetas,
        const float* __restrict__ g4_lmdas,
        const int* __restrict__ tcount, const vf2* __restrict__ trec,
        const int* __restrict__ ecount, const unsigned* __restrict__ erec,
        float* __restrict__ out, int N) {
    __shared__ vf2      sg4[4][66];
    __shared__ unsigned sg2[4][64];
    int w = threadIdx.x >> 6;
    int lane = threadIdx.x & 63;
    int a = blockIdx.x * 4 + w;
    if (a >= N) return;
    int A = an[a];

    // ---- G4 ----
    int c18 = lane % 18;            // combo = (e*2+l)*3+z
    int g3  = lane / 18;            // record sub-slot 0..2 (3 for lanes 54-63)
    int g3r = (g3 > 2) ? 0 : g3;
    int z_c = c18 % 3;
    int l_c = (c18 / 3) % 2;
    int e_c = c18 / 6;
    float eta0, eta1, eta2w, zv0, zv1, zv2, lm0, lm1, lm2;
    {
        int k0 = A * 3 + 0, k1 = A * 3 + 1, k2 = A * 3 + 2;
        eta0 = g4_etas[k0 * 3 + e_c]; eta1 = g4_etas[k1 * 3 + e_c]; eta2w = g4_etas[k2 * 3 + e_c];
        zv0  = g4_zetas[k0 * 3 + z_c]; zv1 = g4_zetas[k1 * 3 + z_c]; zv2 = g4_zetas[k2 * 3 + z_c];
        lm0  = g4_lmdas[k0 * 2 + l_c]; lm1 = g4_lmdas[k1 * 2 + l_c]; lm2 = g4_lmdas[k2 * 2 + l_c];
    }
    auto zsel = [](float z) -> int {
        return (z == 1.0f) ? 0 : (z == 2.0f) ? 1 : (z == 4.0f) ? 2 : 3;
    };
    int zs0 = zsel(zv0), zs1 = zsel(zv1), zs2 = zsel(zv2);
    bool fastz = __all(zs0 < 3 && zs1 < 3 && zs2 < 3);

    int n_t = min(tcount[a], CAP_T);
    const vf2* rec = trec + (size_t)a * CAP_T;
    float acc0 = 0.0f, acc1 = 0.0f, acc2 = 0.0f;
    vf2 zr; zr.x = 0.0f; zr.y = 0.0f;
    for (int b0 = 0; b0 < n_t; b0 += 64) {
        int nch = min(64, n_t - b0);
        vf2 rv = zr;
        if (lane < nch) rv = __builtin_nontemporal_load(rec + b0 + lane);
        sg4[w][lane] = rv;
        if (lane < 2) sg4[w][64 + lane] = zr;
        asm volatile("s_waitcnt lgkmcnt(0)" ::: "memory");
        int niter = (nch + 2) / 3;
        if (fastz) {
            for (int i = 0; i < niter; ++i) {
                vf2 b = sg4[w][i * 3 + g3r];
                unsigned w0 = __float_as_uint(b.x);
                int btr = (int)(w0 & 3u);
                float cut3 = (float)((w0 >> 2) & 0x3FFFu) * (1.0f / 16383.0f);
                float c = fmaf((float)(w0 >> 16), 2.0f / 65535.0f, -1.0f);
                float eta_r = (btr == 0) ? eta0 : (btr == 1) ? eta1 : eta2w;
                float lm_r  = (btr == 0) ? lm0  : (btr == 1) ? lm1  : lm2;
                int   zs_r  = (btr == 0) ? zs0  : (btr == 1) ? zs1  : zs2;
                float p1 = fabsf(fmaf(lm_r, c, 1.0f));
                float p2 = p1 * p1;
                float p4 = p2 * p2;
                float cl = (zs_r == 0) ? p1 : (zs_r == 1) ? p2 * 0.5f : p4 * 0.125f;
                float v = cl * __expf(-eta_r * b.y) * cut3;
                acc0 += (btr == 0) ? v : 0.0f;
                acc1 += (btr == 1) ? v : 0.0f;
                acc2 += (btr == 2) ? v : 0.0f;
            }
        } else {
            for (int i = 0; i < niter; ++i) {
                vf2 b = sg4[w][i * 3 + g3r];
                unsigned w0 = __float_as_uint(b.x);
                int btr = (int)(w0 & 3u);
                float cut3 = (float)((w0 >> 2) & 0x3FFFu) * (1.0f / 16383.0f);
                float c = fmaf((float)(w0 >> 16), 2.0f / 65535.0f, -1.0f);
                float eta_r = (btr == 0) ? eta0 : (btr == 1) ? eta1 : eta2w;
                float lm_r  = (btr == 0) ? lm0  : (btr == 1) ? lm1  : lm2;
                float zv_r  = (btr == 0) ? zv0  : (btr == 1) ? zv1  : zv2;
                float p1 = fabsf(fmaf(lm_r, c, 1.0f));
                float cl = exp2f(fmaf(zv_r, __log2f(p1), 1.0f - zv_r));
                float v = cl * __expf(-eta_r * b.y) * cut3;
                acc0 += (btr == 0) ? v : 0.0f;
                acc1 += (btr == 1) ? v : 0.0f;
                acc2 += (btr == 2) ? v : 0.0f;
            }
        }
    }
    {
        int cc = lane / 3;          // combo (valid for lane < 54)
        int tt = lane - cc * 3;     // trip
        float s0a = __shfl(acc0, cc),      s1a = __shfl(acc1, cc),      s2a = __shfl(acc2, cc);
        float s0b = __shfl(acc0, cc + 18), s1b = __shfl(acc1, cc + 18), s2b = __shfl(acc2, cc + 18);
        float s0c = __shfl(acc0, cc + 36), s1c = __shfl(acc1, cc + 36), s2c = __shfl(acc2, cc + 36);
        float va = (tt == 0) ? s0a : (tt == 1) ? s1a : s2a;
        float vb = (tt == 0) ? s0b : (tt == 1) ? s1b : s2b;
        float vc = (tt == 0) ? s0c : (tt == 1) ? s1c : s2c;
        if (lane < 54) out[(size_t)a * 70 + 16 + lane] += va + vb + vc;
    }

    // ---- G2 ----
    int c16 = lane & 15;            // col = i*2+s
    int g4g = lane >> 4;            // record sub-slot 0..3
    int s_c = c16 & 1;
    int i_c = c16 >> 1;
    float eta2 = g2_etas[(s_c * 2 + A) * 8 + i_c];
    int n_e = min(ecount[a], CAP_E);
    const unsigned* erc = erec + (size_t)a * CAP_E;
    float accg = 0.0f;
    for (int b0 = 0; b0 < n_e; b0 += 64) {
        int nch = min(64, n_e - b0);
        unsigned rv = 0u;
        if (lane < nch) rv = __builtin_nontemporal_load(erc + b0 + lane);
        sg2[w][lane] = rv;
        asm volatile("s_waitcnt lgkmcnt(0)" ::: "memory");
        int niter = (nch + 3) / 4;
        for (int i = 0; i < niter; ++i) {
            unsigned pk = sg2[w][i * 4 + g4g];
            int sp = (int)(pk & 1u);
            float d = dec_R(pk);
            float fcv = (float)((pk >> 1) & 0x7FFFu) * (1.0f / 32767.0f);
            float v = fcv * __expf(-eta2 * d * d);
            accg += (sp == s_c) ? v : 0.0f;
        }
    }
    {
        float r0 = __shfl(accg, lane);
        float r1 = __shfl(accg, lane + 16);
        float r2 = __shfl(accg, lane + 32);
        float r3 = __shfl(accg, lane + 48);
        if (lane < 16) out[(size_t)a * 70 + lane] += r0 + r1 + r2 + r3;
    }
}

// ---------------- fallback path (direct atomics) ----------------

__global__ void acsf_edges_kernel(const int* __restrict__ an,
                                  const int* __restrict__ ei,
                                  const float* __restrict__ D,
                                  const float* __restrict__ g2_etas,
                                  float2* __restrict__ edata,
                                  float* __restrict__ out,
                                  int E, int use_ws) {
    int e = blockIdx.x * blockDim.x + threadIdx.x;
    if (e >= E) return;
    float d = D[e];
    float cut2 = fc_dev(d);
    if (use_ws) edata[e] = make_float2(d, cut2);
    int src = ei[e];
    int tgt = ei[E + e];
    int as = an[src];
    int at = an[tgt];
    float d2 = d * d;
    const float* eta = g2_etas + (as * 2 + at) * 8;
    float* row = out + (size_t)tgt * 70 + as;
#pragma unroll
    for (int i = 0; i < 8; ++i)
        atomicAdd(row + 2 * i, cut2 * __expf(-eta[i] * d2));
}

__global__ void acsf_triplets_kernel(const int* __restrict__ an,
                                     const int* __restrict__ ei,
                                     const float* __restrict__ D,
                                     const float2* __restrict__ edata,
                                     const int* __restrict__ id3_ba,
                                     const int* __restrict__ id3_ca,
                                     const float* __restrict__ cosphi,
                                     const float* __restrict__ g4_etas,
                                     const float* __restrict__ g4_zetas,
                                     const float* __restrict__ g4_lmdas,
                                     float* __restrict__ out,
                                     int T, int E, int use_ws) {
    int t = blockIdx.x * blockDim.x + threadIdx.x;
    if (t >= T) return;
    int eba = id3_ba[t];
    int eca = id3_ca[t];
    if (eba <= eca) return;
    float R_ba, R_ca, fba, fca;
    if (use_ws) {
        float2 va = edata[eba];
        float2 vb = edata[eca];
        R_ba = va.x; fba = va.y;
        R_ca = vb.x; fca = vb.y;
    } else {
        R_ba = D[eba]; R_ca = D[eca];
        fba = fc_dev(R_ba); fca = fc_dev(R_ca);
    }
    if (R_ba >= 6.0f || R_ca >= 6.0f) return;
    float cph = cosphi[t];
    float Rbc2 = R_ba * R_ba + R_ca * R_ca - 2.0f * R_ba * R_ca * cph;
    float Rm2 = fmaxf(Rbc2, 1e-12f);
    float R_bc = sqrtf(Rm2);
    if (R_bc >= 6.0f) return;
    int seg = ei[E + eba];
    int A = an[seg];
    int sb = an[ei[eba]];
    int sc = an[ei[eca]];
    int trip = sb + sc;
    int k4 = A * 3 + trip;
    float cut3 = fba * fca * fc_dev(R_bc);
    float r2sum = Rm2 + R_ba * R_ba + R_ca * R_ca;
    const float* eta = g4_etas + k4 * 3;
    const float* zet = g4_zetas + k4 * 3;
    const float* lmd = g4_lmdas + k4 * 2;
    float rad[3];
#pragma unroll
    for (int e2 = 0; e2 < 3; ++e2)
        rad[e2] = __expf(-eta[e2] * r2sum) * cut3;
    float lg0 = __log2f(fabsf(fmaf(lmd[0], cph, 1.0f)));
    float lg1 = __log2f(fabsf(fmaf(lmd[1], cph, 1.0f)));
    float* row = out + (size_t)seg * 70 + 16 + trip;
#pragma unroll
    for (int z = 0; z < 3; ++z) {
        float zv = zet[z], bse = 1.0f - zv;
        float c0 = exp2f(fmaf(zv, lg0, bse));
        float c1 = exp2f(fmaf(zv, lg1, bse));
#pragma unroll
        for (int e2 = 0; e2 < 3; ++e2) {
            atomicAdd(row + ((e2 * 2 + 0) * 3 + z) * 3, c0 * rad[e2]);
            atomicAdd(row + ((e2 * 2 + 1) * 3 + z) * 3, c1 * rad[e2]);
        }
    }
}

// ---------------- host ----------------

extern "C" void kernel_launch(void* const* d_in, const int* in_sizes, int n_in,
                              void* d_out, int out_size, void* d_ws, size_t ws_size,
                              hipStream_t stream) {
    const int*   an       = (const int*)d_in[0];
    const int*   ei       = (const int*)d_in[1];
    const float* D        = (const float*)d_in[2];
    const int*   id3_ba   = (const int*)d_in[3];
    const int*   id3_ca   = (const int*)d_in[4];
    const float* cosphi   = (const float*)d_in[5];
    const float* g2_etas  = (const float*)d_in[6];
    const float* g4_etas  = (const float*)d_in[7];
    const float* g4_zetas = (const float*)d_in[8];
    const float* g4_lmdas = (const float*)d_in[9];
    (void)n_in;

    int N = in_sizes[0];
    int E = in_sizes[2];
    int T = in_sizes[3];
    float* out = (float*)d_out;

    size_t trec_b  = (size_t)N * CAP_T * sizeof(vf2);
    size_t epack_b = (size_t)((E + 1) & ~1) * sizeof(unsigned);
    size_t erec_b  = (size_t)N * CAP_E * sizeof(unsigned);
    size_t cnt_b   = (size_t)N * sizeof(int) * 2;
    size_t need = trec_b + epack_b + erec_b + cnt_b;

    const int blk = 256;
    (void)hipMemsetAsync(d_out, 0, (size_t)out_size * sizeof(float), stream);

    if (ws_size >= need && N <= 32767) {
        char* p = (char*)d_ws;
        vf2*      trec  = (vf2*)p;             p += trec_b;
        unsigned* epack = (unsigned*)p;        p += epack_b;
        unsigned* erec  = (unsigned*)p;        p += erec_b;
        int*      tcount = (int*)p;
        int*      ecount = tcount + N;
        (void)hipMemsetAsync(tcount, 0, cnt_b, stream);

        int ethreads = (E + 1) / 2;
        edges_bin_kernel<<<(ethreads + blk - 1) / blk, blk, 0, stream>>>(
            an, ei, D, g2_etas, epack, ecount, erec, out, E);
        int tthreads = (T + 3) / 4;
        trip_bin_kernel<<<(tthreads + blk - 1) / blk, blk, 0, stream>>>(
            epack, id3_ba, id3_ca, cosphi, an,
            g4_etas, g4_zetas, g4_lmdas, tcount, trec, out, T);
        gather_kernel<<<(N + 3) / 4, blk, 0, stream>>>(
            an, g2_etas, g4_etas, g4_zetas, g4_lmdas,
            tcount, trec, ecount, erec, out, N);
    } else {
        int use_ws = (ws_size >= (size_t)E * sizeof(float2)) ? 1 : 0;
        float2* edata = (float2*)d_ws;
        acsf_edges_kernel<<<(E + blk - 1) / blk, blk, 0, stream>>>(
            an, ei, D, g2_etas, edata, out, E, use_ws);
        acsf_triplets_kernel<<<(T + blk - 1) / blk, blk, 0, stream>>>(
            an, ei, D, edata, id3_ba, id3_ca, cosphi,
            g4_etas, g4_zetas, g4_lmdas, out, T, E, use_ws);
    }
}